// Round 1
// baseline (105.581 us; speedup 1.0000x reference)
//
#include <hip/hip_runtime.h>

// CNF vector field + exact divergence, split-kernel edition.
//   dx  = tanh(tanh([x,t]W1+b1)W2+b2)W3+b3, /2
//   div = 0.5 * d1^T (W2 ∘ (W1[:64]^T W3^T)) d2
// R8: the fused kernel's phase 2 forced every block to read the whole 1MB
//   Bpack (256 blocks -> 256MB L2 ~7.4us) and wasted half its MFMAs on the
//   unused quadrants (h@G, d@W2). Split into prep -> pack -> gemm -> epilogue:
//   gemm tiles BM=128/BN=64 (96MB L2 total), pack's LDS-bound W1^T W3^T dot is
//   hoisted to a one-shot M kernel block-range (same f32 accumulation order ->
//   bit-identical G). Harness residue (256MB ws fill ~41us + restores) is the
//   floor; only the ~30us kernel portion is addressed here.

constexpr int HD = 512;
constexpr int DD = 64;
constexpr int SB = 8;

typedef __attribute__((ext_vector_type(8))) short bf16x8;
typedef __attribute__((ext_vector_type(4))) float f32x4;

__device__ inline unsigned short f2bf(float f) {
    union { float f; unsigned u; } v; v.f = f;
    return (unsigned short)((v.u + 0x7fffu + ((v.u >> 16) & 1u)) >> 16);
}
__device__ inline float fast_tanh(float xx) {
    float e = __expf(2.f * xx);
    return 1.f - 2.f / (e + 1.f);
}

// ---------------- prep: h1/d1 (blocks 0..255) + M = W1[:64]^T W3^T (256..319)
__global__ __launch_bounds__(512) void cnf_prep_kernel(
    const float* __restrict__ tptr, const float* __restrict__ x,
    const float* __restrict__ W1, const float* __restrict__ b1,
    const float* __restrict__ W3,
    unsigned short* __restrict__ Apack,   // [2][2048][512] bf16: Ah then Ad
    float* __restrict__ Mws)              // [512][512] f32
{
    __shared__ float4 xsv[65 * 2];
    __shared__ float w1b[64][8];
    const int tid = threadIdx.x;

    if (blockIdx.x < 256) {
        const int s0 = blockIdx.x * SB;
        // stage x rows (drop col 64, append t)
        {
            const float tval = tptr[0];
            for (int e = tid; e < SB * 65; e += 512) {
                int s = e / 65, i = e % 65;
                reinterpret_cast<float*>(xsv)[i * SB + s] =
                    (i == DD) ? tval : x[(s0 + s) * 65 + i];
            }
        }
        __syncthreads();
        // layer 1 fp32; thread = unit u, all 8 samples (verbatim from R7)
        const int u = tid;
        const float bb = b1[u];
        float2 a0 = {bb, bb}, a1 = {bb, bb}, a2 = {bb, bb}, a3 = {bb, bb};
        for (int ib = 0; ib < 64; ib += 8) {
            float w[8];
#pragma unroll
            for (int qq = 0; qq < 8; ++qq) w[qq] = W1[(ib + qq) * HD + u];
#pragma unroll
            for (int qq = 0; qq < 8; ++qq) {
                float4 p = xsv[2 * (ib + qq)], r = xsv[2 * (ib + qq) + 1];
                a0.x += p.x * w[qq]; a0.y += p.y * w[qq];
                a1.x += p.z * w[qq]; a1.y += p.w * w[qq];
                a2.x += r.x * w[qq]; a2.y += r.y * w[qq];
                a3.x += r.z * w[qq]; a3.y += r.w * w[qq];
            }
        }
        {
            float w = W1[64 * HD + u];
            float4 p = xsv[128], r = xsv[129];
            a0.x += p.x * w; a0.y += p.y * w;
            a1.x += p.z * w; a1.y += p.w * w;
            a2.x += r.x * w; a2.y += r.y * w;
            a3.x += r.z * w; a3.y += r.w * w;
        }
        float h[8] = {fast_tanh(a0.x), fast_tanh(a0.y), fast_tanh(a1.x), fast_tanh(a1.y),
                      fast_tanh(a2.x), fast_tanh(a2.y), fast_tanh(a3.x), fast_tanh(a3.y)};
        unsigned short* Ah = Apack;
        unsigned short* Ad = Apack + (size_t)2048 * HD;
#pragma unroll
        for (int s = 0; s < 8; ++s) {
            Ah[(size_t)(s0 + s) * HD + u] = f2bf(h[s]);
            Ad[(size_t)(s0 + s) * HD + u] = f2bf(1.f - h[s] * h[s]);
        }
    } else {
        // M[k][n] = sum_i W1[i][k] * W3[n][i]; 8 k-rows per block, n = tid
        const int kb = (blockIdx.x - 256) * 8;
        {
            int i = tid >> 3, kq = tid & 7;
            w1b[i][kq] = W1[i * HD + kb + kq];
        }
        __syncthreads();
        const int n = tid;
        float m8[8] = {0.f, 0.f, 0.f, 0.f, 0.f, 0.f, 0.f, 0.f};
        for (int i = 0; i < 64; i += 4) {
            float4 w3v = *reinterpret_cast<const float4*>(W3 + n * DD + i);
#pragma unroll
            for (int q = 0; q < 4; ++q) {
                float wv = (q == 0) ? w3v.x : (q == 1) ? w3v.y : (q == 2) ? w3v.z : w3v.w;
                float4 a = *reinterpret_cast<const float4*>(&w1b[i + q][0]);
                float4 c = *reinterpret_cast<const float4*>(&w1b[i + q][4]);
                m8[0] += a.x * wv; m8[1] += a.y * wv; m8[2] += a.z * wv; m8[3] += a.w * wv;
                m8[4] += c.x * wv; m8[5] += c.y * wv; m8[6] += c.z * wv; m8[7] += c.w * wv;
            }
        }
#pragma unroll
        for (int j = 0; j < 8; ++j) Mws[(size_t)(kb + j) * HD + n] = m8[j];
    }
}

// ---------------- pack: Bpack = bf16 fragment-ordered [W2 | W2∘M] ------------
// chunk c = (mat*32 + t)*16 + kk; lane l: 8 bf16 = B[kk*32+(l>>4)*8+j][t*16+(l&15)]
// (layout verified R5/R6). 8 units of 64 threads per block; pure elementwise now.
__global__ __launch_bounds__(512) void cnf_pack_kernel(
    const float* __restrict__ W2, const float* __restrict__ Mws,
    unsigned short* __restrict__ Bpack)
{
    const int b = blockIdx.x * 8 + (threadIdx.x >> 6);   // 0..1023
    const int mat = b >> 9, t = (b >> 4) & 31, kk = b & 15;
    const int l = threadIdx.x & 63;
    const int q = l >> 4, nl = l & 15;
    const int n = t * 16 + nl;
    unsigned short o[8];
#pragma unroll
    for (int j = 0; j < 8; ++j) {
        int k = kk * 32 + q * 8 + j;
        float w = W2[k * HD + n];
        if (mat) w *= Mws[(size_t)k * HD + n];
        o[j] = f2bf(w);
    }
    uint4 pk;
    pk.x = (unsigned)o[0] | ((unsigned)o[1] << 16);
    pk.y = (unsigned)o[2] | ((unsigned)o[3] << 16);
    pk.z = (unsigned)o[4] | ((unsigned)o[5] << 16);
    pk.w = (unsigned)o[6] | ((unsigned)o[7] << 16);
    reinterpret_cast<uint4*>(Bpack)[b * 64 + l] = pk;
}

// ---------------- gemm: C1 = Ah@W2, C2 = Ad@G; BM=128, BN=64 -----------------
// grid 256: b = g*128 + rt*8 + ct. 4 waves, wave w owns rows row0+w*32..+32.
// A/B frags read direct from L2 (both already fragment-ordered); 3-stage prefetch.
__global__ __launch_bounds__(256) void cnf_gemm_kernel(
    const unsigned short* __restrict__ Apack,
    const unsigned short* __restrict__ Bpack,
    float* __restrict__ C)                    // [2][2048][512] f32
{
    const int b = blockIdx.x;
    const int g  = b >> 7;
    const int rt = (b >> 3) & 15;
    const int ct = b & 7;
    const int tid = threadIdx.x, wave = tid >> 6, lane = tid & 63;
    const int row0 = rt * 128 + wave * 32;

    const bf16x8* A  = reinterpret_cast<const bf16x8*>(Apack) + (size_t)g * 2048 * 64;
    const bf16x8* Bf = reinterpret_cast<const bf16x8*>(Bpack)
                     + (size_t)((g * 32 + ct * 4) * 16) * 64 + lane;
    const int a0 = (row0 + (lane & 15)) * 64 + (lane >> 4);   // frag idx, + kk*4
    const int a1 = a0 + 16 * 64;

    f32x4 acc[2][4];
#pragma unroll
    for (int rg = 0; rg < 2; ++rg)
#pragma unroll
        for (int i = 0; i < 4; ++i) acc[rg][i] = (f32x4){0.f, 0.f, 0.f, 0.f};

    bf16x8 p0[12], p1[12], p2[12];     // 2-kk super-batches, 3-stage rotate
    auto loadSB = [&](bf16x8* d, int kk) {
        d[0] = A[a0 + kk * 4];
        d[1] = A[a1 + kk * 4];
#pragma unroll
        for (int i = 0; i < 4; ++i) d[2 + i] = Bf[(i * 16 + kk) * 64];
        d[6] = A[a0 + (kk + 1) * 4];
        d[7] = A[a1 + (kk + 1) * 4];
#pragma unroll
        for (int i = 0; i < 4; ++i) d[8 + i] = Bf[(i * 16 + kk + 1) * 64];
    };
    auto mfmaSB = [&](const bf16x8* d) {
#pragma unroll
        for (int i = 0; i < 4; ++i) {
            acc[0][i] = __builtin_amdgcn_mfma_f32_16x16x32_bf16(d[0], d[2 + i], acc[0][i], 0, 0, 0);
            acc[1][i] = __builtin_amdgcn_mfma_f32_16x16x32_bf16(d[1], d[2 + i], acc[1][i], 0, 0, 0);
        }
#pragma unroll
        for (int i = 0; i < 4; ++i) {
            acc[0][i] = __builtin_amdgcn_mfma_f32_16x16x32_bf16(d[6], d[8 + i], acc[0][i], 0, 0, 0);
            acc[1][i] = __builtin_amdgcn_mfma_f32_16x16x32_bf16(d[7], d[8 + i], acc[1][i], 0, 0, 0);
        }
    };

    loadSB(p0, 0);
    loadSB(p1, 2);
#pragma unroll
    for (int kb = 0; kb < 8; ++kb) {
        const int c3 = kb % 3, n3 = (kb + 2) % 3;
        bf16x8* cur = (c3 == 0) ? p0 : (c3 == 1) ? p1 : p2;
        bf16x8* nxt = (n3 == 0) ? p0 : (n3 == 1) ? p1 : p2;
        if (kb < 6) loadSB(nxt, (kb + 2) * 2);
        mfmaSB(cur);
    }

    float* Cg = C + (size_t)g * 2048 * HD;
    const int colb = ct * 64 + (lane & 15);
#pragma unroll
    for (int rg = 0; rg < 2; ++rg) {
        const int rbase = row0 + rg * 16 + (lane >> 4) * 4;
#pragma unroll
        for (int i = 0; i < 4; ++i) {
#pragma unroll
            for (int reg = 0; reg < 4; ++reg)
                Cg[(size_t)(rbase + reg) * HD + colb + i * 16] = acc[rg][i][reg];
        }
    }
}

// ---------------- epilogue: tanh+b2, divergence, layer 3, outputs ------------
__global__ __launch_bounds__(512) void cnf_out_kernel(
    const float* __restrict__ C,      // [2][2048][512]
    const float* __restrict__ b2v, const float* __restrict__ W3,
    const float* __restrict__ b3, float* __restrict__ out)
{
    __shared__ float4 h2v[HD * 2];    // [m][s0-3],[m][s4-7]
    __shared__ float opart[8 * 512];
    __shared__ float divred[8][8];    // [wave][sample]
    const int tid = threadIdx.x;
    const int s0 = blockIdx.x * SB;
    const int wave = tid >> 6, lane = tid & 63;
    const float* C1 = C;
    const float* C2 = C + (size_t)2048 * HD;

    // h2 = tanh(C1 + b2); div partials = C2 * (1 - h2^2); thread = unit m
    {
        const int m = tid;
        const float bb = b2v[m];
        float hh[8], dp[8];
#pragma unroll
        for (int s = 0; s < 8; ++s) {
            float c1 = C1[(size_t)(s0 + s) * HD + m];
            float c2 = C2[(size_t)(s0 + s) * HD + m];
            float h = fast_tanh(c1 + bb);
            hh[s] = h;
            dp[s] = c2 * (1.f - h * h);
        }
        h2v[2 * m]     = (float4){hh[0], hh[1], hh[2], hh[3]};
        h2v[2 * m + 1] = (float4){hh[4], hh[5], hh[6], hh[7]};
#pragma unroll
        for (int s = 0; s < 8; ++s) {
#pragma unroll
            for (int off = 32; off > 0; off >>= 1) dp[s] += __shfl_down(dp[s], off);
        }
        if (lane == 0) {
#pragma unroll
            for (int s = 0; s < 8; ++s) divred[wave][s] = dp[s];
        }
    }
    __syncthreads();

    // layer 3 fp32; part = wave, k = lane; 64 m's per part (verbatim from R7)
    {
        const int k = lane, part = wave;
        float o[8];
#pragma unroll
        for (int q = 0; q < 8; ++q) o[q] = 0.f;
        const int mb = part * 64;
        for (int mm = 0; mm < 64; mm += 4) {
            float w[4];
#pragma unroll
            for (int q = 0; q < 4; ++q) w[q] = W3[(mb + mm + q) * DD + k];
#pragma unroll
            for (int q = 0; q < 4; ++q) {
                const int m = mb + mm + q;
                float4 ha = h2v[2 * m], hb = h2v[2 * m + 1];
                o[0] += ha.x * w[q]; o[1] += ha.y * w[q];
                o[2] += ha.z * w[q]; o[3] += ha.w * w[q];
                o[4] += hb.x * w[q]; o[5] += hb.y * w[q];
                o[6] += hb.z * w[q]; o[7] += hb.w * w[q];
            }
        }
#pragma unroll
        for (int q = 0; q < 8; ++q) opart[part * 512 + q * 64 + k] = o[q];
    }
    __syncthreads();

    {
        const int s = tid >> 6, k = tid & 63;
        float sum = b3[k];
#pragma unroll
        for (int p = 0; p < 8; ++p) sum += opart[p * 512 + s * 64 + k];
        out[(s0 + s) * 65 + k] = 0.5f * sum;
    }
    if (tid < 8) {
        float ds = 0.f;
#pragma unroll
        for (int w = 0; w < 8; ++w) ds += divred[w][tid];
        out[(s0 + tid) * 65 + DD] = 0.5f * ds;
    }
}

extern "C" void kernel_launch(void* const* d_in, const int* in_sizes, int n_in,
                              void* d_out, int out_size, void* d_ws, size_t ws_size,
                              hipStream_t stream) {
    const float* t  = (const float*)d_in[0];
    const float* x  = (const float*)d_in[1];
    const float* W1 = (const float*)d_in[2];
    const float* b1 = (const float*)d_in[3];
    const float* W2 = (const float*)d_in[4];
    const float* b2 = (const float*)d_in[5];
    const float* W3 = (const float*)d_in[6];
    const float* b3 = (const float*)d_in[7];
    float* out = (float*)d_out;

    unsigned short* Bpack = (unsigned short*)d_ws;                       // 1 MB
    float*          Mws   = (float*)((char*)d_ws + (1 << 20));           // 1 MB
    unsigned short* Apack = (unsigned short*)((char*)d_ws + (2 << 20));  // 4 MB
    float*          Cws   = (float*)((char*)d_ws + (6 << 20));           // 8 MB

    cnf_prep_kernel<<<320, 512, 0, stream>>>(t, x, W1, b1, W3, Apack, Mws);
    cnf_pack_kernel<<<128, 512, 0, stream>>>(W2, Mws, Bpack);
    cnf_gemm_kernel<<<256, 256, 0, stream>>>(Apack, Bpack, Cws);
    cnf_out_kernel<<<256, 512, 0, stream>>>(Cws, b2, W3, b3, out);
}